// Round 13
// baseline (1326.761 us; speedup 1.0000x reference)
//
#include <hip/hip_runtime.h>
#include <cstdint>
#include <cstddef>

// SAMGuidedCrossAttention: B=4, C=256, H=W=256, heads=8, ws=8, d=32
// Round 13 = r12 (512-thr fused QKV, full-line V) + CROSS-TILE PIPELINE:
//   Block = one image row = 4 tiles of 64 pos. Prefetch holds ONE tensor
//   (32 scalar floats = 32 VGPR) at a time:
//     issue(xkv,t+1) before V-GEMM  -> packed into bufKV after post-V barrier
//     issue(xq, t+1) during V-store -> packed into bufQ after next barrier
//   Max live = acc32+afr16+ld32+addr ~95 VGPR (r12 measured 60; headroom).
//   Buffer lifetimes: V-epi -> bufQ (xq dead); new-KV pack -> bufKV (dead
//   after same barrier); 4 barriers/tile.
//   attn_conv: r11/r12 unchanged (XCD swizzle, wpT frags, full-line V).

typedef __attribute__((ext_vector_type(8))) short bfx8;   // 8 bf16 (4 VGPR)
typedef __attribute__((ext_vector_type(4))) float f32x4;  // MFMA acc

#define HW 65536
#define NC 256
#define QKV_STRIDE 16777216UL  // ushorts per tensor per batch (1024*8*64*32)

__device__ __forceinline__ unsigned short f2bf(float f) {
  union { float f; unsigned u; } v; v.f = f;
  unsigned r = v.u + 0x7FFFu + ((v.u >> 16) & 1u);  // RNE
  return (unsigned short)(r >> 16);
}

__global__ __launch_bounds__(256) void prep_weights(
    const float* __restrict__ wq, const float* __restrict__ wk,
    const float* __restrict__ wv, const float* __restrict__ wp,
    unsigned short* __restrict__ dst) {
  int i = blockIdx.x * 256 + threadIdx.x;  // 65536 elements
  dst[i]          = f2bf(wq[i]);
  dst[i + 65536]  = f2bf(wk[i]);
  dst[i + 131072] = f2bf(wv[i]);
  int e = i & 7, lane = (i >> 3) & 63, ks = (i >> 9) & 7, ot = i >> 12;
  int src = (ot * 16 + (lane & 15)) * 256 + ks * 32 + (lane >> 4) * 8 + e;
  dst[i + 196608] = f2bf(wp[src]);
}

// GEMM pass (8 waves): wave ow owns rows [ow*32, +32); N = all 64.
__device__ __forceinline__ void gemm_pass512(
    const unsigned short* __restrict__ wmat, const unsigned char* __restrict__ smem,
    int ow, int g, int qh, f32x4 (&acc)[2][4]) {
#pragma unroll
  for (int i = 0; i < 2; ++i)
#pragma unroll
    for (int j = 0; j < 4; ++j) acc[i][j] = (f32x4){0.f, 0.f, 0.f, 0.f};

  bfx8 afr[2];
#pragma unroll
  for (int mt = 0; mt < 2; ++mt)
    afr[mt] = *(const bfx8*)(wmat + (ow * 32 + mt * 16 + qh) * 256 + g * 8);

  for (int ks = 0; ks < 8; ++ks) {
    bfx8 naf[2];
    if (ks < 7) {
#pragma unroll
      for (int mt = 0; mt < 2; ++mt)
        naf[mt] = *(const bfx8*)(wmat + (ow * 32 + mt * 16 + qh) * 256 + (ks + 1) * 32 + g * 8);
    }
#pragma unroll
    for (int nt = 0; nt < 4; ++nt) {
      unsigned byte = ((unsigned)((nt * 16 + qh) * 512 + ks * 64 + g * 16)) ^
                      (((unsigned)(qh & 7)) << 4);
      bfx8 bfr = *(const bfx8*)(smem + byte);
#pragma unroll
      for (int mt = 0; mt < 2; ++mt)
        acc[mt][nt] = __builtin_amdgcn_mfma_f32_16x16x32_bf16(afr[mt], bfr, acc[mt][nt], 0, 0, 0);
    }
    if (ks < 7) { afr[0] = naf[0]; afr[1] = naf[1]; }
  }
}

// Direct windowed store for Q/K layout [win*8+head][pos 64][d 32] (+bias).
__device__ __forceinline__ void store_qk512(
    const f32x4 (&acc)[2][4], const float* __restrict__ bias,
    unsigned short* __restrict__ outw, int n0, int ow, int g, int qh) {
  const int h_img = n0 >> 8, w0b = n0 & 255;
#pragma unroll
  for (int mt = 0; mt < 2; ++mt) {
    int o = ow * 32 + mt * 16 + g * 4;
    f32x4 bb = *(const f32x4*)&bias[o];
    int head = o >> 5, dbase = o & 31;
#pragma unroll
    for (int nt = 0; nt < 4; ++nt) {
      int n = nt * 16 + qh;
      int w_img = w0b + n;
      int win = ((h_img >> 3) << 5) + (w_img >> 3);
      int pos = ((h_img & 7) << 3) + (w_img & 7);
      f32x4 a = acc[mt][nt];
      uint2 pv;
      pv.x = (unsigned)f2bf(a.x + bb.x) | ((unsigned)f2bf(a.y + bb.y) << 16);
      pv.y = (unsigned)f2bf(a.z + bb.z) | ((unsigned)f2bf(a.w + bb.w) << 16);
      *(uint2*)&outw[((size_t)(win * 8 + head) * 64 + pos) * 32 + dbase] = pv;
    }
  }
}

// ---------------- fused QKV projection GEMM (cross-tile pipelined) --------
// grid (256, 1, NB), 512 thr (8 waves). Block = one image row, 4 tiles.
__global__ __launch_bounds__(512) void qkv_gemm(
    const float* __restrict__ xq, const float* __restrict__ xkv,
    const unsigned short* __restrict__ wbf,
    const float* __restrict__ bq, const float* __restrict__ bk,
    const float* __restrict__ bv,
    unsigned short* __restrict__ q_w, unsigned short* __restrict__ k_w,
    unsigned short* __restrict__ v_w, int batch0, int batched) {
  __shared__ __align__(16) unsigned char bufQ[32768];   // xq stage | V-epi
  __shared__ __align__(16) unsigned char bufKV[32768];  // xkv stage (K and V)

  const int tid = threadIdx.x;
  const int lane = tid & 63;
  const int wid = tid >> 6;        // 0..7 = ow
  const int g = lane >> 4;
  const int qh = lane & 15;
  const int row = (int)blockIdx.x; // image row 0..255
  const int batch = batch0 + blockIdx.z;
  const size_t qofs = batched ? (size_t)blockIdx.z * QKV_STRIDE : 0;
  const float* xq_b = xq + (size_t)batch * NC * HW;
  const float* xkv_b = xkv + (size_t)batch * NC * HW;

  const int sn = tid & 63;   // staging lane -> contiguous n
  const int oc = tid >> 6;   // 0..7 channel-octet group

  float ld[32];  // one tensor's tile slice in flight (32 VGPR)
  auto issue = [&](const float* x, int t) {
    const int n0 = row * 256 + t * 64;
#pragma unroll
    for (int it = 0; it < 4; ++it) {
      int c8 = (it * 8 + oc) * 8;
      const float* xp = x + (size_t)c8 * HW + n0 + sn;
#pragma unroll
      for (int j = 0; j < 8; ++j) ld[it * 8 + j] = xp[(size_t)j * HW];
    }
  };
  auto pack = [&](unsigned char* dst) {
#pragma unroll
    for (int it = 0; it < 4; ++it) {
      int c8 = (it * 8 + oc) * 8;
      uint4 u;
      u.x = (unsigned)f2bf(ld[it * 8 + 0]) | ((unsigned)f2bf(ld[it * 8 + 1]) << 16);
      u.y = (unsigned)f2bf(ld[it * 8 + 2]) | ((unsigned)f2bf(ld[it * 8 + 3]) << 16);
      u.z = (unsigned)f2bf(ld[it * 8 + 4]) | ((unsigned)f2bf(ld[it * 8 + 5]) << 16);
      u.w = (unsigned)f2bf(ld[it * 8 + 6]) | ((unsigned)f2bf(ld[it * 8 + 7]) << 16);
      unsigned byte = ((unsigned)(sn * 512 + c8 * 2)) ^ (((unsigned)(sn & 7)) << 4);
      *(uint4*)(dst + byte) = u;
    }
  };

  // prologue: tile 0 staged directly
  issue(xq_b, 0);  pack(bufQ);
  issue(xkv_b, 0); pack(bufKV);

  for (int t = 0; t < 4; ++t) {
    __syncthreads();  // B0: staged tiles visible
    const int n0 = row * 256 + t * 64;

    f32x4 acc[2][4];
    gemm_pass512(wbf, bufQ, wid, g, qh, acc);              // wq
    store_qk512(acc, bq, q_w + qofs, n0, wid, g, qh);
    gemm_pass512(wbf + 65536, bufKV, wid, g, qh, acc);     // wk
    store_qk512(acc, bk, k_w + qofs, n0, wid, g, qh);
    if (t < 3) issue(xkv_b, t + 1);                        // rides under V-GEMM
    gemm_pass512(wbf + 131072, bufKV, wid, g, qh, acc);    // wv

    __syncthreads();  // B1: all reads of bufQ (Q) and bufKV (K,V) done

    // V epilogue transpose into bufQ (xq dead): [o 256][n 64] bf16,
    // byte = o*128 + n*2 ^ (((o>>2)&7)<<4). Conflicts <= 2-way (free).
#pragma unroll
    for (int mt = 0; mt < 2; ++mt) {
      int o = wid * 32 + mt * 16 + g * 4;
      f32x4 bb = *(const f32x4*)&bv[o];
#pragma unroll
      for (int nt = 0; nt < 4; ++nt) {
        int n = nt * 16 + qh;
        f32x4 a = acc[mt][nt];
        float vj[4] = {a.x + bb.x, a.y + bb.y, a.z + bb.z, a.w + bb.w};
#pragma unroll
        for (int j = 0; j < 4; ++j) {
          unsigned oo = (unsigned)(o + j);
          unsigned byte = (oo * 128 + (unsigned)n * 2) ^ (((oo >> 2) & 7u) << 4);
          *(unsigned short*)(bufQ + byte) = f2bf(vj[j]);
        }
      }
    }
    if (t < 3) pack(bufKV);                                // xkv(t+1) -> bufKV

    __syncthreads();  // B2: V-epi (bufQ) + new KV stage visible

    // V store from bufQ: [win*8+head][rowblk 8][d 32][col 8] (full lines)
    {
      const int h7 = row & 7;
      unsigned short* vw = v_w + qofs;
#pragma unroll
      for (int it = 0; it < 4; ++it) {
        int id = it * 512 + tid;
        unsigned o = (unsigned)(id >> 3);
        int oct = id & 7;
        unsigned byte = (o * 128 + (unsigned)oct * 16) ^ (((o >> 2) & 7u) << 4);
        uint4 val = *(const uint4*)(bufQ + byte);
        int head = (int)(o >> 5), dd = (int)(o & 31);
        int win = ((row >> 3) << 5) + t + oct;  // w0b>>3 == t*64>>3? no:
        // w0b = t*64 -> base window col = t*8? NO: t*64/8 = t*8.
        win = ((row >> 3) << 5) + t * 8 + oct;
        *(uint4*)&vw[(size_t)(win * 8 + head) * 2048 + (size_t)(h7 * 256 + dd * 8)] = val;
      }
    }
    if (t < 3) issue(xq_b, t + 1);                         // rides under V-store

    __syncthreads();  // B3: V-store reads of bufQ done
    if (t < 3) pack(bufQ);                                 // xq(t+1) -> bufQ
    // loop-top B0 publishes the new stages
  }
}

// ---------------- fused windowed attention + output conv ----------------
// Block: 256 thr (4 waves) = 1 window. Wave handles heads {wid, wid+4}.
__global__ __launch_bounds__(256) void attn_conv(
    const unsigned short* __restrict__ q_w, const unsigned short* __restrict__ k_w,
    const unsigned short* __restrict__ v_w, const unsigned short* __restrict__ wpT,
    const float* __restrict__ bp, float* __restrict__ out, int batch0, int batched) {
  __shared__ unsigned short P_lds[4][2048];  // per-wave P half-tile [64 q][32 k], swizzled
  __shared__ unsigned short y_t[16384];      // [pos 64][c 256] bf16, swizzled

  const int tid = threadIdx.x;
  const int lane = tid & 63;
  const int wid = tid >> 6;
  const int g = lane >> 4;
  const int qh = lane & 15;
  const int bid = blockIdx.x;
  // XCD-chunked swizzle: XCD j owns winl [j*128, +128).
  const int winl = ((bid & 7) << 7) | (bid >> 3);
  const int batch = batch0 + blockIdx.z;
  const size_t qofs = batched ? (size_t)blockIdx.z * QKV_STRIDE : 0;
  const float scale = 0.17677669529663687f;  // 1/sqrt(32)

  char* pbase = (char*)&P_lds[wid][0];

#pragma unroll
  for (int hi = 0; hi < 2; ++hi) {
    const int head = wid + hi * 4;
    const unsigned short* qb = q_w + qofs + (size_t)(winl * 8 + head) * 2048;
    const unsigned short* kb = k_w + qofs + (size_t)(winl * 8 + head) * 2048;
    const unsigned short* vb = v_w + qofs + (size_t)(winl * 8 + head) * 2048;

    bfx8 kf[4], qf[4];
#pragma unroll
    for (int t = 0; t < 4; ++t) {
      kf[t] = *(const bfx8*)(kb + (t * 16 + qh) * 32 + g * 8);
      qf[t] = *(const bfx8*)(qb + (t * 16 + qh) * 32 + g * 8);
    }
    // S^T[kpos][q] = sum_d K[kpos][d] * Q[q][d]
    f32x4 zero = {0.f, 0.f, 0.f, 0.f};
    f32x4 st[4][4];
#pragma unroll
    for (int kt = 0; kt < 4; ++kt)
#pragma unroll
      for (int qt = 0; qt < 4; ++qt)
        st[kt][qt] = __builtin_amdgcn_mfma_f32_16x16x32_bf16(kf[kt], qf[qt], zero, 0, 0, 0);

    // softmax over kpos (rows of S^T)
    float rv[4];
#pragma unroll
    for (int qt = 0; qt < 4; ++qt) {
      float m = -1e30f;
#pragma unroll
      for (int kt = 0; kt < 4; ++kt) {
        f32x4 v = st[kt][qt];
        m = fmaxf(m, fmaxf(fmaxf(v.x, v.y), fmaxf(v.z, v.w)));
      }
      m = fmaxf(m, __shfl_xor(m, 16, 64));
      m = fmaxf(m, __shfl_xor(m, 32, 64));
      float ssum = 0.f;
#pragma unroll
      for (int kt = 0; kt < 4; ++kt) {
        f32x4 v = st[kt][qt], e;
        e.x = __expf((v.x - m) * scale);
        e.y = __expf((v.y - m) * scale);
        e.z = __expf((v.z - m) * scale);
        e.w = __expf((v.w - m) * scale);
        ssum += e.x + e.y + e.z + e.w;
        st[kt][qt] = e;
      }
      ssum += __shfl_xor(ssum, 16, 64);
      ssum += __shfl_xor(ssum, 32, 64);
      rv[qt] = 1.f / ssum;
    }

    // PV: out^T[d][q] = sum_k V^T[d][k] * P
    f32x4 ot[2][4];
#pragma unroll
    for (int dt = 0; dt < 2; ++dt)
#pragma unroll
      for (int qt = 0; qt < 4; ++qt) ot[dt][qt] = zero;

#pragma unroll
    for (int s = 0; s < 2; ++s) {
#pragma unroll
      for (int qt = 0; qt < 4; ++qt) {
        int q = qt * 16 + qh;
        unsigned sw = ((unsigned)(q & 3)) << 4;
        float r = rv[qt];
#pragma unroll
        for (int k2 = 0; k2 < 2; ++k2) {
          f32x4 e = st[s * 2 + k2][qt];
          uint2 pv;
          pv.x = (unsigned)f2bf(e.x * r) | ((unsigned)f2bf(e.y * r) << 16);
          pv.y = (unsigned)f2bf(e.z * r) | ((unsigned)f2bf(e.w * r) << 16);
          unsigned byte = ((unsigned)q * 64 + (unsigned)(k2 * 32 + g * 8)) ^ sw;
          *(uint2*)(pbase + byte) = pv;
        }
      }
      bfx8 pf[4];
#pragma unroll
      for (int qt = 0; qt < 4; ++qt) {
        int q = qt * 16 + qh;
        unsigned byte = ((unsigned)q * 64 + (unsigned)(g * 16)) ^ (((unsigned)(q & 3)) << 4);
        pf[qt] = *(const bfx8*)(pbase + byte);
      }
#pragma unroll
      for (int dt = 0; dt < 2; ++dt) {
        // V layout [rowblk 8][d 32][col 8]: pos-run s*32+g*8 -> rowblk s*4+g
        bfx8 vf = *(const bfx8*)(vb + (s * 4 + g) * 256 + (dt * 16 + qh) * 8);
#pragma unroll
        for (int qt = 0; qt < 4; ++qt)
          ot[dt][qt] = __builtin_amdgcn_mfma_f32_16x16x32_bf16(vf, pf[qt], ot[dt][qt], 0, 0, 0);
      }
    }

    // attention output -> y_t[pos][c] (swizzled), c = head*32 + d
#pragma unroll
    for (int dt = 0; dt < 2; ++dt) {
      int cb = head * 32 + dt * 16 + g * 4;
#pragma unroll
      for (int qt = 0; qt < 4; ++qt) {
        int pos = qt * 16 + qh;
        f32x4 a = ot[dt][qt];
        uint2 pv;
        pv.x = (unsigned)f2bf(a.x) | ((unsigned)f2bf(a.y) << 16);
        pv.y = (unsigned)f2bf(a.z) | ((unsigned)f2bf(a.w) << 16);
        unsigned byte = ((unsigned)pos * 512 + (unsigned)cb * 2) ^ (((unsigned)(pos & 7)) << 4);
        *(uint2*)((char*)y_t + byte) = pv;
      }
    }
  }
  __syncthreads();

  // output conv: out[o][pos] = sum_c wp[o][c] * y[c][pos]; wave wid: o in [64*wid, +64)
  f32x4 acc[4][4];
#pragma unroll
  for (int i = 0; i < 4; ++i)
#pragma unroll
    for (int j = 0; j < 4; ++j) acc[i][j] = (f32x4){0.f, 0.f, 0.f, 0.f};

  for (int ks = 0; ks < 8; ++ks) {
    bfx8 af[4];
#pragma unroll
    for (int mt = 0; mt < 4; ++mt)
      af[mt] = *(const bfx8*)(wpT + (((wid * 4 + mt) * 8 + ks) * 64 + lane) * 8);
#pragma unroll
    for (int nt = 0; nt < 4; ++nt) {
      int pos = nt * 16 + qh;
      unsigned byte = ((unsigned)pos * 512 + (unsigned)(ks * 64 + g * 16)) ^ (((unsigned)(pos & 7)) << 4);
      bfx8 bfr = *(const bfx8*)((char*)y_t + byte);
#pragma unroll
      for (int mt = 0; mt < 4; ++mt)
        acc[mt][nt] = __builtin_amdgcn_mfma_f32_16x16x32_bf16(af[mt], bfr, acc[mt][nt], 0, 0, 0);
    }
  }

  const int wrow = winl >> 5, wcol = winl & 31;
  float* ob_ = out + (size_t)batch * NC * HW;
#pragma unroll
  for (int mt = 0; mt < 4; ++mt) {
    int o0 = wid * 64 + mt * 16 + g * 4;
    float b0 = bp[o0], b1 = bp[o0 + 1], b2 = bp[o0 + 2], b3 = bp[o0 + 3];
#pragma unroll
    for (int nt = 0; nt < 4; ++nt) {
      int pos = nt * 16 + qh;
      int h_img = wrow * 8 + (pos >> 3);
      int w_img = wcol * 8 + (pos & 7);
      float* pp = ob_ + (size_t)o0 * HW + h_img * 256 + w_img;
      pp[0]      = acc[mt][nt].x + b0;
      pp[HW]     = acc[mt][nt].y + b1;
      pp[2 * HW] = acc[mt][nt].z + b2;
      pp[3 * HW] = acc[mt][nt].w + b3;
    }
  }
}

extern "C" void kernel_launch(void* const* d_in, const int* in_sizes, int n_in,
                              void* d_out, int out_size, void* d_ws, size_t ws_size,
                              hipStream_t stream) {
  const float* q_feat = (const float*)d_in[0];
  const float* kv_feat = (const float*)d_in[1];
  const float* wq = (const float*)d_in[2];
  const float* bq = (const float*)d_in[3];
  const float* wk = (const float*)d_in[4];
  const float* bk = (const float*)d_in[5];
  const float* wv = (const float*)d_in[6];
  const float* bv = (const float*)d_in[7];
  const float* wp = (const float*)d_in[8];
  const float* bp = (const float*)d_in[9];
  float* out = (float*)d_out;

  unsigned short* wbf = (unsigned short*)d_ws;  // 4 x 65536 bf16 = 512 KB
  const size_t need_batched = 524288ul + 12ul * QKV_STRIDE * 2ul;  // ~403 MB

  hipLaunchKernelGGL(prep_weights, dim3(256), dim3(256), 0, stream, wq, wk, wv, wp, wbf);

  if (ws_size >= need_batched) {
    // all-batch path: 2 big launches
    unsigned short* q_w = wbf + 262144;
    unsigned short* k_w = q_w + 4 * QKV_STRIDE;
    unsigned short* v_w = k_w + 4 * QKV_STRIDE;
    hipLaunchKernelGGL(qkv_gemm, dim3(256, 1, 4), dim3(512), 0, stream,
                       q_feat, kv_feat, wbf, bq, bk, bv, q_w, k_w, v_w, 0, 1);
    hipLaunchKernelGGL(attn_conv, dim3(1024, 1, 4), dim3(256), 0, stream,
                       q_w, k_w, v_w, wbf + 196608, bp, out, 0, 1);
  } else {
    // per-batch fallback (~97 MB workspace)
    unsigned short* q_w = wbf + 262144;
    unsigned short* k_w = q_w + QKV_STRIDE;
    unsigned short* v_w = k_w + QKV_STRIDE;
    for (int b = 0; b < 4; ++b) {
      hipLaunchKernelGGL(qkv_gemm, dim3(256, 1, 1), dim3(512), 0, stream,
                         q_feat, kv_feat, wbf, bq, bk, bv, q_w, k_w, v_w, b, 0);
      hipLaunchKernelGGL(attn_conv, dim3(1024, 1, 1), dim3(256), 0, stream,
                         q_w, k_w, v_w, wbf + 196608, bp, out, b, 0);
    }
  }
}

// Round 14
// 521.913 us; speedup vs baseline: 2.5421x; 2.5421x over previous
//
#include <hip/hip_runtime.h>
#include <cstdint>
#include <cstddef>

// SAMGuidedCrossAttention: B=4, C=256, H=W=256, heads=8, ws=8, d=32
// Round 14 = r12 (proven 535us: 512-thr fused QKV, full-line V layout)
// + DUAL-TENSOR STAGE: all 64 loads (xq+xkv) issued before any pack, so the
// block eats ONE HBM latency exposure per tile instead of two sequential
// ones (r12's VGPR=60 proves the compiler didn't hoist across the packs).
// Arrays die before the first gemm_pass -> no overlap with acc/afr -> no
// spill (the r4/r6/r8/r13 failure mode was prefetch live ACROSS a pass).
// Peak live ~90 VGPR < 128 -> still 4 waves/SIMD, 16 waves/CU.
//   attn_conv: r11/r12 unchanged (XCD swizzle, wpT frags, full-line V).

typedef __attribute__((ext_vector_type(8))) short bfx8;   // 8 bf16 (4 VGPR)
typedef __attribute__((ext_vector_type(4))) float f32x4;  // MFMA acc

#define HW 65536
#define NC 256
#define QKV_STRIDE 16777216UL  // ushorts per tensor per batch (1024*8*64*32)

__device__ __forceinline__ unsigned short f2bf(float f) {
  union { float f; unsigned u; } v; v.f = f;
  unsigned r = v.u + 0x7FFFu + ((v.u >> 16) & 1u);  // RNE
  return (unsigned short)(r >> 16);
}

__global__ __launch_bounds__(256) void prep_weights(
    const float* __restrict__ wq, const float* __restrict__ wk,
    const float* __restrict__ wv, const float* __restrict__ wp,
    unsigned short* __restrict__ dst) {
  int i = blockIdx.x * 256 + threadIdx.x;  // 65536 elements
  dst[i]          = f2bf(wq[i]);
  dst[i + 65536]  = f2bf(wk[i]);
  dst[i + 131072] = f2bf(wv[i]);
  int e = i & 7, lane = (i >> 3) & 63, ks = (i >> 9) & 7, ot = i >> 12;
  int src = (ot * 16 + (lane & 15)) * 256 + ks * 32 + (lane >> 4) * 8 + e;
  dst[i + 196608] = f2bf(wp[src]);
}

// GEMM pass (8 waves): wave ow owns rows [ow*32, +32); N = all 64.
__device__ __forceinline__ void gemm_pass512(
    const unsigned short* __restrict__ wmat, const unsigned char* __restrict__ smem,
    int ow, int g, int qh, f32x4 (&acc)[2][4]) {
#pragma unroll
  for (int i = 0; i < 2; ++i)
#pragma unroll
    for (int j = 0; j < 4; ++j) acc[i][j] = (f32x4){0.f, 0.f, 0.f, 0.f};

  bfx8 afr[2];
#pragma unroll
  for (int mt = 0; mt < 2; ++mt)
    afr[mt] = *(const bfx8*)(wmat + (ow * 32 + mt * 16 + qh) * 256 + g * 8);

  for (int ks = 0; ks < 8; ++ks) {
    bfx8 naf[2];
    if (ks < 7) {
#pragma unroll
      for (int mt = 0; mt < 2; ++mt)
        naf[mt] = *(const bfx8*)(wmat + (ow * 32 + mt * 16 + qh) * 256 + (ks + 1) * 32 + g * 8);
    }
#pragma unroll
    for (int nt = 0; nt < 4; ++nt) {
      unsigned byte = ((unsigned)((nt * 16 + qh) * 512 + ks * 64 + g * 16)) ^
                      (((unsigned)(qh & 7)) << 4);
      bfx8 bfr = *(const bfx8*)(smem + byte);
#pragma unroll
      for (int mt = 0; mt < 2; ++mt)
        acc[mt][nt] = __builtin_amdgcn_mfma_f32_16x16x32_bf16(afr[mt], bfr, acc[mt][nt], 0, 0, 0);
    }
    if (ks < 7) { afr[0] = naf[0]; afr[1] = naf[1]; }
  }
}

// Direct windowed store for Q/K layout [win*8+head][pos 64][d 32] (+bias).
__device__ __forceinline__ void store_qk512(
    const f32x4 (&acc)[2][4], const float* __restrict__ bias,
    unsigned short* __restrict__ outw, int n0, int ow, int g, int qh) {
  const int h_img = n0 >> 8, w0b = n0 & 255;
#pragma unroll
  for (int mt = 0; mt < 2; ++mt) {
    int o = ow * 32 + mt * 16 + g * 4;
    f32x4 bb = *(const f32x4*)&bias[o];
    int head = o >> 5, dbase = o & 31;
#pragma unroll
    for (int nt = 0; nt < 4; ++nt) {
      int n = nt * 16 + qh;
      int w_img = w0b + n;
      int win = ((h_img >> 3) << 5) + (w_img >> 3);
      int pos = ((h_img & 7) << 3) + (w_img & 7);
      f32x4 a = acc[mt][nt];
      uint2 pv;
      pv.x = (unsigned)f2bf(a.x + bb.x) | ((unsigned)f2bf(a.y + bb.y) << 16);
      pv.y = (unsigned)f2bf(a.z + bb.z) | ((unsigned)f2bf(a.w + bb.w) << 16);
      *(uint2*)&outw[((size_t)(win * 8 + head) * 64 + pos) * 32 + dbase] = pv;
    }
  }
}

// ---------------- fused QKV projection GEMM ----------------
// grid (1024, 1, NB), 512 thr (8 waves). Block = one 64-pos tile, Q+K+V.
__global__ __launch_bounds__(512) void qkv_gemm(
    const float* __restrict__ xq, const float* __restrict__ xkv,
    const unsigned short* __restrict__ wbf,
    const float* __restrict__ bq, const float* __restrict__ bk,
    const float* __restrict__ bv,
    unsigned short* __restrict__ q_w, unsigned short* __restrict__ k_w,
    unsigned short* __restrict__ v_w, int batch0, int batched) {
  __shared__ __align__(16) unsigned char bufQ[32768];   // xq stage | V-epi
  __shared__ __align__(16) unsigned char bufKV[32768];  // xkv stage (K and V)

  const int tid = threadIdx.x;
  const int lane = tid & 63;
  const int wid = tid >> 6;        // 0..7 = ow
  const int g = lane >> 4;
  const int qh = lane & 15;
  const int n0 = (int)blockIdx.x * 64;
  const int batch = batch0 + blockIdx.z;
  const size_t qofs = batched ? (size_t)blockIdx.z * QKV_STRIDE : 0;
  const float* xq_b = xq + (size_t)batch * NC * HW;
  const float* xkv_b = xkv + (size_t)batch * NC * HW;

  // ---- dual-tensor stage: issue ALL loads, then pack both ----
  {
    const int sn = tid & 63;   // lane -> contiguous n (coalesced 256B/row)
    const int oc = tid >> 6;   // 0..7 channel-octet group
    float aq[32], akv[32];
#pragma unroll
    for (int it = 0; it < 4; ++it) {
      int c8 = (it * 8 + oc) * 8;
      const float* xpq = xq_b + (size_t)c8 * HW + n0 + sn;
      const float* xpk = xkv_b + (size_t)c8 * HW + n0 + sn;
#pragma unroll
      for (int j = 0; j < 8; ++j) aq[it * 8 + j] = xpq[(size_t)j * HW];
#pragma unroll
      for (int j = 0; j < 8; ++j) akv[it * 8 + j] = xpk[(size_t)j * HW];
    }
#pragma unroll
    for (int it = 0; it < 4; ++it) {
      int c8 = (it * 8 + oc) * 8;
      unsigned byte = ((unsigned)(sn * 512 + c8 * 2)) ^ (((unsigned)(sn & 7)) << 4);
      uint4 u;
      u.x = (unsigned)f2bf(aq[it * 8 + 0]) | ((unsigned)f2bf(aq[it * 8 + 1]) << 16);
      u.y = (unsigned)f2bf(aq[it * 8 + 2]) | ((unsigned)f2bf(aq[it * 8 + 3]) << 16);
      u.z = (unsigned)f2bf(aq[it * 8 + 4]) | ((unsigned)f2bf(aq[it * 8 + 5]) << 16);
      u.w = (unsigned)f2bf(aq[it * 8 + 6]) | ((unsigned)f2bf(aq[it * 8 + 7]) << 16);
      *(uint4*)(bufQ + byte) = u;
      uint4 v;
      v.x = (unsigned)f2bf(akv[it * 8 + 0]) | ((unsigned)f2bf(akv[it * 8 + 1]) << 16);
      v.y = (unsigned)f2bf(akv[it * 8 + 2]) | ((unsigned)f2bf(akv[it * 8 + 3]) << 16);
      v.z = (unsigned)f2bf(akv[it * 8 + 4]) | ((unsigned)f2bf(akv[it * 8 + 5]) << 16);
      v.w = (unsigned)f2bf(akv[it * 8 + 6]) | ((unsigned)f2bf(akv[it * 8 + 7]) << 16);
      *(uint4*)(bufKV + byte) = v;
    }
  }
  __syncthreads();

  f32x4 acc[2][4];
  gemm_pass512(wbf, bufQ, wid, g, qh, acc);              // wq
  store_qk512(acc, bq, q_w + qofs, n0, wid, g, qh);
  gemm_pass512(wbf + 65536, bufKV, wid, g, qh, acc);     // wk
  store_qk512(acc, bk, k_w + qofs, n0, wid, g, qh);
  gemm_pass512(wbf + 131072, bufKV, wid, g, qh, acc);    // wv

  __syncthreads();  // all LDS reads (incl. bufQ from Q pass) done
  // V epilogue transpose into bufQ: [o 256][n 64] bf16 (128B rows),
  // byte = o*128 + n*2 ^ (((o>>2)&7)<<4). Conflicts <= 2-way (free).
#pragma unroll
  for (int mt = 0; mt < 2; ++mt) {
    int o = wid * 32 + mt * 16 + g * 4;
    f32x4 bb = *(const f32x4*)&bv[o];
#pragma unroll
    for (int nt = 0; nt < 4; ++nt) {
      int n = nt * 16 + qh;
      f32x4 a = acc[mt][nt];
      float vj[4] = {a.x + bb.x, a.y + bb.y, a.z + bb.z, a.w + bb.w};
#pragma unroll
      for (int j = 0; j < 4; ++j) {
        unsigned oo = (unsigned)(o + j);
        unsigned byte = (oo * 128 + (unsigned)n * 2) ^ (((oo >> 2) & 7u) << 4);
        *(unsigned short*)(bufQ + byte) = f2bf(vj[j]);
      }
    }
  }
  __syncthreads();
  // V store: [win*8+head][rowblk 8][d 32][col 8] -> 512B contiguous per
  // (win,head), 8x128B FULL lines per instruction (r11 proven layout).
  const int h_img = n0 >> 8, w0b = n0 & 255;
  const int h7 = h_img & 7;
  unsigned short* vw = v_w + qofs;
#pragma unroll
  for (int it = 0; it < 4; ++it) {
    int id = it * 512 + tid;
    unsigned o = (unsigned)(id >> 3);   // channel 0..255
    int oct = id & 7;                   // window octet within tile
    unsigned byte = (o * 128 + (unsigned)oct * 16) ^ (((o >> 2) & 7u) << 4);
    uint4 val = *(const uint4*)(bufQ + byte);  // Vt[o][cols oct*8..+8]
    int head = (int)(o >> 5), dd = (int)(o & 31);
    int win = ((h_img >> 3) << 5) + (w0b >> 3) + oct;
    *(uint4*)&vw[(size_t)(win * 8 + head) * 2048 + (size_t)(h7 * 256 + dd * 8)] = val;
  }
}

// ---------------- fused windowed attention + output conv ----------------
// Block: 256 thr (4 waves) = 1 window. Wave handles heads {wid, wid+4}.
__global__ __launch_bounds__(256) void attn_conv(
    const unsigned short* __restrict__ q_w, const unsigned short* __restrict__ k_w,
    const unsigned short* __restrict__ v_w, const unsigned short* __restrict__ wpT,
    const float* __restrict__ bp, float* __restrict__ out, int batch0, int batched) {
  __shared__ unsigned short P_lds[4][2048];  // per-wave P half-tile [64 q][32 k], swizzled
  __shared__ unsigned short y_t[16384];      // [pos 64][c 256] bf16, swizzled

  const int tid = threadIdx.x;
  const int lane = tid & 63;
  const int wid = tid >> 6;
  const int g = lane >> 4;
  const int qh = lane & 15;
  const int bid = blockIdx.x;
  // XCD-chunked swizzle: XCD j owns winl [j*128, +128).
  const int winl = ((bid & 7) << 7) | (bid >> 3);
  const int batch = batch0 + blockIdx.z;
  const size_t qofs = batched ? (size_t)blockIdx.z * QKV_STRIDE : 0;
  const float scale = 0.17677669529663687f;  // 1/sqrt(32)

  char* pbase = (char*)&P_lds[wid][0];

#pragma unroll
  for (int hi = 0; hi < 2; ++hi) {
    const int head = wid + hi * 4;
    const unsigned short* qb = q_w + qofs + (size_t)(winl * 8 + head) * 2048;
    const unsigned short* kb = k_w + qofs + (size_t)(winl * 8 + head) * 2048;
    const unsigned short* vb = v_w + qofs + (size_t)(winl * 8 + head) * 2048;

    bfx8 kf[4], qf[4];
#pragma unroll
    for (int t = 0; t < 4; ++t) {
      kf[t] = *(const bfx8*)(kb + (t * 16 + qh) * 32 + g * 8);
      qf[t] = *(const bfx8*)(qb + (t * 16 + qh) * 32 + g * 8);
    }
    // S^T[kpos][q] = sum_d K[kpos][d] * Q[q][d]
    f32x4 zero = {0.f, 0.f, 0.f, 0.f};
    f32x4 st[4][4];
#pragma unroll
    for (int kt = 0; kt < 4; ++kt)
#pragma unroll
      for (int qt = 0; qt < 4; ++qt)
        st[kt][qt] = __builtin_amdgcn_mfma_f32_16x16x32_bf16(kf[kt], qf[qt], zero, 0, 0, 0);

    // softmax over kpos (rows of S^T)
    float rv[4];
#pragma unroll
    for (int qt = 0; qt < 4; ++qt) {
      float m = -1e30f;
#pragma unroll
      for (int kt = 0; kt < 4; ++kt) {
        f32x4 v = st[kt][qt];
        m = fmaxf(m, fmaxf(fmaxf(v.x, v.y), fmaxf(v.z, v.w)));
      }
      m = fmaxf(m, __shfl_xor(m, 16, 64));
      m = fmaxf(m, __shfl_xor(m, 32, 64));
      float ssum = 0.f;
#pragma unroll
      for (int kt = 0; kt < 4; ++kt) {
        f32x4 v = st[kt][qt], e;
        e.x = __expf((v.x - m) * scale);
        e.y = __expf((v.y - m) * scale);
        e.z = __expf((v.z - m) * scale);
        e.w = __expf((v.w - m) * scale);
        ssum += e.x + e.y + e.z + e.w;
        st[kt][qt] = e;
      }
      ssum += __shfl_xor(ssum, 16, 64);
      ssum += __shfl_xor(ssum, 32, 64);
      rv[qt] = 1.f / ssum;
    }

    // PV: out^T[d][q] = sum_k V^T[d][k] * P
    f32x4 ot[2][4];
#pragma unroll
    for (int dt = 0; dt < 2; ++dt)
#pragma unroll
      for (int qt = 0; qt < 4; ++qt) ot[dt][qt] = zero;

#pragma unroll
    for (int s = 0; s < 2; ++s) {
#pragma unroll
      for (int qt = 0; qt < 4; ++qt) {
        int q = qt * 16 + qh;
        unsigned sw = ((unsigned)(q & 3)) << 4;
        float r = rv[qt];
#pragma unroll
        for (int k2 = 0; k2 < 2; ++k2) {
          f32x4 e = st[s * 2 + k2][qt];
          uint2 pv;
          pv.x = (unsigned)f2bf(e.x * r) | ((unsigned)f2bf(e.y * r) << 16);
          pv.y = (unsigned)f2bf(e.z * r) | ((unsigned)f2bf(e.w * r) << 16);
          unsigned byte = ((unsigned)q * 64 + (unsigned)(k2 * 32 + g * 8)) ^ sw;
          *(uint2*)(pbase + byte) = pv;
        }
      }
      bfx8 pf[4];
#pragma unroll
      for (int qt = 0; qt < 4; ++qt) {
        int q = qt * 16 + qh;
        unsigned byte = ((unsigned)q * 64 + (unsigned)(g * 16)) ^ (((unsigned)(q & 3)) << 4);
        pf[qt] = *(const bfx8*)(pbase + byte);
      }
#pragma unroll
      for (int dt = 0; dt < 2; ++dt) {
        // V layout [rowblk 8][d 32][col 8]: pos-run s*32+g*8 -> rowblk s*4+g
        bfx8 vf = *(const bfx8*)(vb + (s * 4 + g) * 256 + (dt * 16 + qh) * 8);
#pragma unroll
        for (int qt = 0; qt < 4; ++qt)
          ot[dt][qt] = __builtin_amdgcn_mfma_f32_16x16x32_bf16(vf, pf[qt], ot[dt][qt], 0, 0, 0);
      }
    }

    // attention output -> y_t[pos][c] (swizzled), c = head*32 + d
#pragma unroll
    for (int dt = 0; dt < 2; ++dt) {
      int cb = head * 32 + dt * 16 + g * 4;
#pragma unroll
      for (int qt = 0; qt < 4; ++qt) {
        int pos = qt * 16 + qh;
        f32x4 a = ot[dt][qt];
        uint2 pv;
        pv.x = (unsigned)f2bf(a.x) | ((unsigned)f2bf(a.y) << 16);
        pv.y = (unsigned)f2bf(a.z) | ((unsigned)f2bf(a.w) << 16);
        unsigned byte = ((unsigned)pos * 512 + (unsigned)cb * 2) ^ (((unsigned)(pos & 7)) << 4);
        *(uint2*)((char*)y_t + byte) = pv;
      }
    }
  }
  __syncthreads();

  // output conv: out[o][pos] = sum_c wp[o][c] * y[c][pos]; wave wid: o in [64*wid, +64)
  f32x4 acc[4][4];
#pragma unroll
  for (int i = 0; i < 4; ++i)
#pragma unroll
    for (int j = 0; j < 4; ++j) acc[i][j] = (f32x4){0.f, 0.f, 0.f, 0.f};

  for (int ks = 0; ks < 8; ++ks) {
    bfx8 af[4];
#pragma unroll
    for (int mt = 0; mt < 4; ++mt)
      af[mt] = *(const bfx8*)(wpT + (((wid * 4 + mt) * 8 + ks) * 64 + lane) * 8);
#pragma unroll
    for (int nt = 0; nt < 4; ++nt) {
      int pos = nt * 16 + qh;
      unsigned byte = ((unsigned)pos * 512 + (unsigned)(ks * 64 + g * 16)) ^ (((unsigned)(pos & 7)) << 4);
      bfx8 bfr = *(const bfx8*)((char*)y_t + byte);
#pragma unroll
      for (int mt = 0; mt < 4; ++mt)
        acc[mt][nt] = __builtin_amdgcn_mfma_f32_16x16x32_bf16(af[mt], bfr, acc[mt][nt], 0, 0, 0);
    }
  }

  const int wrow = winl >> 5, wcol = winl & 31;
  float* ob_ = out + (size_t)batch * NC * HW;
#pragma unroll
  for (int mt = 0; mt < 4; ++mt) {
    int o0 = wid * 64 + mt * 16 + g * 4;
    float b0 = bp[o0], b1 = bp[o0 + 1], b2 = bp[o0 + 2], b3 = bp[o0 + 3];
#pragma unroll
    for (int nt = 0; nt < 4; ++nt) {
      int pos = nt * 16 + qh;
      int h_img = wrow * 8 + (pos >> 3);
      int w_img = wcol * 8 + (pos & 7);
      float* pp = ob_ + (size_t)o0 * HW + h_img * 256 + w_img;
      pp[0]      = acc[mt][nt].x + b0;
      pp[HW]     = acc[mt][nt].y + b1;
      pp[2 * HW] = acc[mt][nt].z + b2;
      pp[3 * HW] = acc[mt][nt].w + b3;
    }
  }
}

extern "C" void kernel_launch(void* const* d_in, const int* in_sizes, int n_in,
                              void* d_out, int out_size, void* d_ws, size_t ws_size,
                              hipStream_t stream) {
  const float* q_feat = (const float*)d_in[0];
  const float* kv_feat = (const float*)d_in[1];
  const float* wq = (const float*)d_in[2];
  const float* bq = (const float*)d_in[3];
  const float* wk = (const float*)d_in[4];
  const float* bk = (const float*)d_in[5];
  const float* wv = (const float*)d_in[6];
  const float* bv = (const float*)d_in[7];
  const float* wp = (const float*)d_in[8];
  const float* bp = (const float*)d_in[9];
  float* out = (float*)d_out;

  unsigned short* wbf = (unsigned short*)d_ws;  // 4 x 65536 bf16 = 512 KB
  const size_t need_batched = 524288ul + 12ul * QKV_STRIDE * 2ul;  // ~403 MB

  hipLaunchKernelGGL(prep_weights, dim3(256), dim3(256), 0, stream, wq, wk, wv, wp, wbf);

  if (ws_size >= need_batched) {
    // all-batch path: 2 big launches
    unsigned short* q_w = wbf + 262144;
    unsigned short* k_w = q_w + 4 * QKV_STRIDE;
    unsigned short* v_w = k_w + 4 * QKV_STRIDE;
    hipLaunchKernelGGL(qkv_gemm, dim3(1024, 1, 4), dim3(512), 0, stream,
                       q_feat, kv_feat, wbf, bq, bk, bv, q_w, k_w, v_w, 0, 1);
    hipLaunchKernelGGL(attn_conv, dim3(1024, 1, 4), dim3(256), 0, stream,
                       q_w, k_w, v_w, wbf + 196608, bp, out, 0, 1);
  } else {
    // per-batch fallback (~97 MB workspace)
    unsigned short* q_w = wbf + 262144;
    unsigned short* k_w = q_w + QKV_STRIDE;
    unsigned short* v_w = k_w + QKV_STRIDE;
    for (int b = 0; b < 4; ++b) {
      hipLaunchKernelGGL(qkv_gemm, dim3(1024, 1, 1), dim3(512), 0, stream,
                         q_feat, kv_feat, wbf, bq, bk, bv, q_w, k_w, v_w, b, 0);
      hipLaunchKernelGGL(attn_conv, dim3(1024, 1, 1), dim3(256), 0, stream,
                         q_w, k_w, v_w, wbf + 196608, bp, out, b, 0);
    }
  }
}